// Round 3
// baseline (4246.255 us; speedup 1.0000x reference)
//
#include <hip/hip_runtime.h>

typedef unsigned long long u64;
typedef unsigned int u32;

#define NB 4
#define NP 4096
#define MP 2048
#define KN 32
#define FD 64
#define CAP 512
#define PPT 16  // points per thread in fps (256 threads * 16 = 4096)

// Exact (non-contracted) squared distance, matching numpy's f32 evaluation
// order: ((dx*dx + dy*dy) + dz*dz), each op individually rounded.
__device__ __forceinline__ float dist2(float ax, float ay, float az,
                                       float bx, float by, float bz) {
  float dx = ax - bx, dy = ay - by, dz = az - bz;
  return __fadd_rn(__fadd_rn(__fmul_rn(dx, dx), __fmul_rn(dy, dy)),
                   __fmul_rn(dz, dz));
}

__device__ __forceinline__ void fma16(float* acc, float a, const float4* wp) {
#pragma unroll
  for (int u = 0; u < 4; ++u) {
    float4 wv = wp[u];
    acc[u * 4 + 0] = fmaf(a, wv.x, acc[u * 4 + 0]);
    acc[u * 4 + 1] = fmaf(a, wv.y, acc[u * 4 + 1]);
    acc[u * 4 + 2] = fmaf(a, wv.z, acc[u * 4 + 2]);
    acc[u * 4 + 3] = fmaf(a, wv.w, acc[u * 4 + 3]);
  }
}

// Wave64 max-reduce of a nonnegative f32 via DPP (identity 0 from bound_ctrl),
// result broadcast to all lanes through readlane(63).
__device__ __forceinline__ float wave_max_bcast(float x) {
  int v = __float_as_int(x);
#define DPP_STEP(ctrl)                                                     \
  {                                                                        \
    int o = __builtin_amdgcn_update_dpp(0, v, ctrl, 0xF, 0xF, true);       \
    v = __float_as_int(fmaxf(__int_as_float(v), __int_as_float(o)));       \
  }
  DPP_STEP(0x111)  // row_shr:1
  DPP_STEP(0x112)  // row_shr:2
  DPP_STEP(0x114)  // row_shr:4
  DPP_STEP(0x118)  // row_shr:8  -> lane 15/31/47/63 hold row maxes
  DPP_STEP(0x142)  // row_bcast15 -> lane31 = max(0..31), lane63 = max(32..63)
  DPP_STEP(0x143)  // row_bcast31 -> lane63 = max(0..63)
#undef DPP_STEP
  return __int_as_float(__builtin_amdgcn_readlane(v, 63));
}

// ---------------------------------------------------------------------------
// Kernel 1: farthest point sampling. One block per cloud, 256 threads,
// 16 points/thread in REGISTERS (no LDS point mirror). Per iteration:
//   - select candidate coords from regs by maxj (4-level cndmask tree)
//   - DPP wave max + ballot (first lane = lowest index wins ties)
//   - per-wave winner writes a 16B record (val,x,y,z) + idx, ONE barrier
//   - all threads: 4 independent ds_read_b128 + 3-compare merge
//     (strict > keeps lower wave = lower index on ties)
// Coords of the next center come from the record — no dependent LDS read.
// ---------------------------------------------------------------------------
__global__ __launch_bounds__(256) void fps_kernel(const float* __restrict__ pos,
                                                  int* __restrict__ fps_idx) {
  const int b = blockIdx.x;
  const float* p = pos + (size_t)b * NP * 3;
  __shared__ __align__(16) float4 recV[2][4];
  __shared__ __align__(16) int recI[2][4];
  const int t = threadIdx.x;
  const int w = t >> 6;
  const int lane = t & 63;
  const int base = t * PPT;

  // ---- load 16 points (48 floats = 12 float4) into registers ----
  float cx[PPT], cy[PPT], cz[PPT], mind[PPT];
  {
    const float4* P4 = (const float4*)(p + (size_t)base * 3);
    float f[48];
#pragma unroll
    for (int u = 0; u < 12; ++u) {
      float4 v = P4[u];
      f[4 * u + 0] = v.x; f[4 * u + 1] = v.y;
      f[4 * u + 2] = v.z; f[4 * u + 3] = v.w;
    }
#pragma unroll
    for (int j = 0; j < PPT; ++j) {
      cx[j] = f[3 * j + 0]; cy[j] = f[3 * j + 1]; cz[j] = f[3 * j + 2];
    }
  }

  const float q0x = p[0], q0y = p[1], q0z = p[2];
  float maxv = -1.0f;
  int maxj = 0;
#pragma unroll
  for (int j = 0; j < PPT; ++j) {
    const float d = dist2(cx[j], cy[j], cz[j], q0x, q0y, q0z);
    mind[j] = d;
    if (d > maxv) { maxv = d; maxj = j; }  // strict >: first max
  }
  if (t == 0) fps_idx[b * MP] = 0;

  for (int it = 1; it < MP; ++it) {
    // ---- select this thread's candidate coords by maxj (constant-index tree)
    const bool b0 = (maxj & 1) != 0, b1 = (maxj & 2) != 0;
    const bool b2 = (maxj & 4) != 0, b3 = (maxj & 8) != 0;
    float ax[8], ay[8], az[8];
#pragma unroll
    for (int u = 0; u < 8; ++u) {
      ax[u] = b0 ? cx[2 * u + 1] : cx[2 * u];
      ay[u] = b0 ? cy[2 * u + 1] : cy[2 * u];
      az[u] = b0 ? cz[2 * u + 1] : cz[2 * u];
    }
#pragma unroll
    for (int u = 0; u < 4; ++u) {
      ax[u] = b1 ? ax[2 * u + 1] : ax[2 * u];
      ay[u] = b1 ? ay[2 * u + 1] : ay[2 * u];
      az[u] = b1 ? az[2 * u + 1] : az[2 * u];
    }
#pragma unroll
    for (int u = 0; u < 2; ++u) {
      ax[u] = b2 ? ax[2 * u + 1] : ax[2 * u];
      ay[u] = b2 ? ay[2 * u + 1] : ay[2 * u];
      az[u] = b2 ? az[2 * u + 1] : az[2 * u];
    }
    ax[0] = b3 ? ax[1] : ax[0];
    ay[0] = b3 ? ay[1] : ay[0];
    az[0] = b3 ? az[1] : az[0];

    // ---- wave argmax + single-writer record ----
    const float wmax = wave_max_bcast(maxv);
    const u64 bal = __ballot(maxv == wmax);
    const u64 below = (1ull << lane) - 1ull;
    if ((maxv == wmax) && ((bal & below) == 0)) {  // first max lane of wave
      recV[it & 1][w] = make_float4(wmax, ax[0], ay[0], az[0]);
      recI[it & 1][w] = base + maxj;
    }
    __syncthreads();

    // ---- merge 4 wave records; strict > keeps lower wave on ties ----
    const float4 r0 = recV[it & 1][0], r1 = recV[it & 1][1];
    const float4 r2 = recV[it & 1][2], r3 = recV[it & 1][3];
    const int4 ri = *(const int4*)recI[it & 1];
    const bool s01 = r1.x > r0.x, s23 = r3.x > r2.x;
    const float4 ma = s01 ? r1 : r0;
    const int ia = s01 ? ri.y : ri.x;
    const float4 mb = s23 ? r3 : r2;
    const int ib = s23 ? ri.w : ri.z;
    const bool sab = mb.x > ma.x;
    const float4 mm = sab ? mb : ma;
    const int im = sab ? ib : ia;
    if (t == 0) fps_idx[b * MP + it] = im;

    // ---- update mind against new center (coords straight from record) ----
    const float ccx = mm.y, ccy = mm.z, ccz = mm.w;
    maxv = -1.0f; maxj = 0;
#pragma unroll
    for (int j = 0; j < PPT; ++j) {
      const float d = dist2(cx[j], cy[j], cz[j], ccx, ccy, ccz);
      const float nm = fminf(mind[j], d);
      mind[j] = nm;
      if (nm > maxv) { maxv = nm; maxj = j; }
    }
    // ping-pong slots + the single barrier make the next write safe: slot
    // (it&1) is rewritten only at it+2, after barrier(it+1) which follows
    // every wave's read of iteration it.
  }
}

// ---------------------------------------------------------------------------
// Kernel 2: radius-kNN. One wave per query (4 waves/block). Compacts all
// within-radius candidates into LDS (ballot compaction), then extracts the
// 32 smallest (d2,idx) keys via wave-wide u64 min-reduction.
// Also writes pos_out and batch_out (exact gathers).
// ---------------------------------------------------------------------------
__global__ __launch_bounds__(256) void knn_kernel(const float* __restrict__ pos,
                                                  const int* __restrict__ fps_idx,
                                                  int* __restrict__ nbr,
                                                  float* __restrict__ pos_out,
                                                  float* __restrict__ batch_out) {
  __shared__ u64 list[4][CAP];
  const int t = threadIdx.x;
  const int w = t >> 6;
  const int lane = t & 63;
  const int qg = blockIdx.x * 4 + w;  // 0..8191
  const int b = qg >> 11;
  const float* p = pos + (size_t)b * NP * 3;
  const int pidx = fps_idx[qg];
  const float qx = p[3 * pidx], qy = p[3 * pidx + 1], qz = p[3 * pidx + 2];

  int base = 0;
  for (int rnd = 0; rnd < NP / 64; ++rnd) {
    const int j = rnd * 64 + lane;
    const float d2 = dist2(p[3 * j], p[3 * j + 1], p[3 * j + 2], qx, qy, qz);
    const bool pred = (d2 <= 0.04f);  // 0.04f == f32(R*R) boundary, exact
    const u64 bal = __ballot(pred);
    if (pred) {
      const int slot = base + (int)__popcll(bal & ((1ull << lane) - 1ull));
      if (slot < CAP) list[w][slot] = ((u64)__float_as_uint(d2) << 32) | (u32)j;
    }
    base += (int)__popcll(bal);
  }
  const int L = base < CAP ? base : CAP;
  __syncthreads();

  u64 mk[8];
#pragma unroll
  for (int s = 0; s < 8; ++s) {
    const int sl = lane + s * 64;
    mk[s] = (sl < L) ? list[w][sl] : ~0ull;
  }
  u64 lmin = mk[0];
#pragma unroll
  for (int s = 1; s < 8; ++s) lmin = (mk[s] < lmin) ? mk[s] : lmin;

  int myNbr = -1;
  for (int r = 0; r < KN; ++r) {
    u64 m = lmin;
#pragma unroll
    for (int off = 32; off >= 1; off >>= 1) {
      u64 om = __shfl_xor(m, off, 64);
      m = (om < m) ? om : m;
    }
    if (m == ~0ull) break;  // wave-uniform: fewer than 32 in-radius
    if (lane == r) myNbr = (int)(m & 0xFFFFFFFFu);
    if (lmin == m) {  // exactly one lane (keys unique)
#pragma unroll
      for (int s = 0; s < 8; ++s) if (mk[s] == m) mk[s] = ~0ull;
      lmin = mk[0];
#pragma unroll
      for (int s = 1; s < 8; ++s) lmin = (mk[s] < lmin) ? mk[s] : lmin;
    }
  }
  if (lane < KN) nbr[(size_t)qg * KN + lane] = myNbr;
  if (lane == 0) {
    pos_out[qg * 3 + 0] = qx;
    pos_out[qg * 3 + 1] = qy;
    pos_out[qg * 3 + 2] = qz;
    batch_out[qg] = (float)b;
  }
}

// ---------------------------------------------------------------------------
// Kernel 3: gather + 3-layer MLP + masked max aggregation.
// Block = 256 threads handles 2 queries (64 neighbor rows). Weights staged
// per-layer into a shared 17KB buffer (W3 streamed in two k-halves).
// Aggregation: relu outputs >= 0 and self-neighbor always valid, so
// 0-initialized atomicMax on float bits is exact.
// ---------------------------------------------------------------------------
__global__ __launch_bounds__(256) void mlp_kernel(
    const float* __restrict__ x, const float* __restrict__ pos,
    const int* __restrict__ fps_idx, const int* __restrict__ nbr,
    const float* __restrict__ W1, const float* __restrict__ b1,
    const float* __restrict__ W2, const float* __restrict__ b2,
    const float* __restrict__ W3, const float* __restrict__ b3,
    float* __restrict__ aggG) {
  __shared__ __align__(16) float inB[64][68];  // 67 cols used (x .. rel)
  __shared__ __align__(16) float hB[64][68];
  __shared__ __align__(16) float wB[4352];     // W1(4288) / W2(4096) / W3-half(4096)
  __shared__ u32 agg[2][128];
  __shared__ int vrow[64];
  const int t = threadIdx.x;
  const int q0 = blockIdx.x * 2;

  ((u32*)agg)[t] = 0u;  // 256 entries exactly
  for (int i = t; i < 1072; i += 256) ((float4*)wB)[i] = ((const float4*)W1)[i];
  {
    const int r = t >> 2, qu = t & 3;
    const int qg = q0 + (r >> 5);
    const int nid = nbr[(size_t)qg * KN + (r & 31)];
    const int gid = (nid < 0) ? 0 : nid;
    const int bb = qg >> 11;
    const float4* xr =
        (const float4*)(x + ((size_t)bb * NP + gid) * FD + qu * 16);
#pragma unroll
    for (int u = 0; u < 4; ++u) {
      float4 v = xr[u];
      inB[r][qu * 16 + u * 4 + 0] = v.x;
      inB[r][qu * 16 + u * 4 + 1] = v.y;
      inB[r][qu * 16 + u * 4 + 2] = v.z;
      inB[r][qu * 16 + u * 4 + 3] = v.w;
    }
    if (qu == 0) {
      vrow[r] = nid;
      const float* p = pos + (size_t)bb * NP * 3;
      const int pidx = fps_idx[qg];
      inB[r][64] = p[3 * gid + 0] - p[3 * pidx + 0];
      inB[r][65] = p[3 * gid + 1] - p[3 * pidx + 1];
      inB[r][66] = p[3 * gid + 2] - p[3 * pidx + 2];
    }
  }
  __syncthreads();

  const int c0a = (t & 3) * 16;  // layers 1-2: 64 channels
  const int ra = t >> 2;         // row 0..63
  {  // ---- layer 1: 67 -> 64, relu ----
    float acc[16];
#pragma unroll
    for (int c = 0; c < 16; ++c) acc[c] = b1[c0a + c];
    for (int k = 0; k < 67; ++k)
      fma16(acc, inB[ra][k], (const float4*)&wB[k * 64 + c0a]);
#pragma unroll
    for (int c = 0; c < 16; ++c) hB[ra][c0a + c] = fmaxf(acc[c], 0.0f);
  }
  __syncthreads();
  for (int i = t; i < 1024; i += 256) ((float4*)wB)[i] = ((const float4*)W2)[i];
  __syncthreads();
  {  // ---- layer 2: 64 -> 64, relu (writes back into inB) ----
    float acc[16];
#pragma unroll
    for (int c = 0; c < 16; ++c) acc[c] = b2[c0a + c];
    for (int k = 0; k < 64; ++k)
      fma16(acc, hB[ra][k], (const float4*)&wB[k * 64 + c0a]);
#pragma unroll
    for (int c = 0; c < 16; ++c) inB[ra][c0a + c] = fmaxf(acc[c], 0.0f);
  }
  __syncthreads();

  // ---- layer 3: 64 -> 128 in two k-halves, then masked max aggregation ----
  const int c0b = (t & 7) * 16;
  const int r0 = (t >> 3) * 2;  // even row pair, never straddles a query
  float acc0[16], acc1[16];
#pragma unroll
  for (int c = 0; c < 16; ++c) { acc0[c] = b3[c0b + c]; acc1[c] = b3[c0b + c]; }
  for (int half = 0; half < 2; ++half) {
    for (int i = t; i < 1024; i += 256)
      ((float4*)wB)[i] = ((const float4*)(W3 + half * 32 * 128))[i];
    __syncthreads();
    for (int k = 0; k < 32; ++k) {
      const float a0 = inB[r0][half * 32 + k];
      const float a1 = inB[r0 + 1][half * 32 + k];
      const float4* wp = (const float4*)&wB[k * 128 + c0b];
      fma16(acc0, a0, wp);
      fma16(acc1, a1, wp);
    }
    __syncthreads();
  }
  {
    const int qq = r0 >> 5;
    const int v0 = vrow[r0], v1 = vrow[r0 + 1];
#pragma unroll
    for (int c = 0; c < 16; ++c) {
      float m = 0.0f;  // == max(0, .) folds the relu; exact (>=1 valid row/query)
      if (v0 >= 0) m = fmaxf(m, acc0[c]);
      if (v1 >= 0) m = fmaxf(m, acc1[c]);
      atomicMax(&agg[qq][c0b + c], __float_as_uint(m));
    }
  }
  __syncthreads();
  aggG[(size_t)(q0 + (t >> 7)) * 128 + (t & 127)] =
      __uint_as_float(agg[t >> 7][t & 127]);
}

// ---------------------------------------------------------------------------
// Kernel 4: out = agg @ Wg + bg. 32 rows/block; Wg staged in two k-halves.
// ---------------------------------------------------------------------------
__global__ __launch_bounds__(256) void wg_kernel(const float* __restrict__ aggG,
                                                 const float* __restrict__ Wg,
                                                 const float* __restrict__ bg,
                                                 float* __restrict__ xout) {
  __shared__ __align__(16) float wL[64 * 128];
  __shared__ __align__(16) float aL[32][132];
  const int t = threadIdx.x;
  const size_t row0 = (size_t)blockIdx.x * 32;
  for (int i = t; i < 1024; i += 256) {
    const int r = i >> 5, qd = i & 31;
    float4 v = ((const float4*)(aggG + (row0 + r) * 128))[qd];
    *((float4*)&aL[r][qd * 4]) = v;
  }
  const int r = t >> 3;
  const int c0 = (t & 7) * 16;
  float acc[16];
#pragma unroll
  for (int c = 0; c < 16; ++c) acc[c] = bg[c0 + c];
  for (int half = 0; half < 2; ++half) {
    __syncthreads();  // protects wL overwrite; also orders aL staging (half 0)
    for (int i = t; i < 2048; i += 256)
      ((float4*)wL)[i] = ((const float4*)(Wg + half * 64 * 128))[i];
    __syncthreads();
    for (int k = 0; k < 64; ++k)
      fma16(acc, aL[r][half * 64 + k], (const float4*)&wL[k * 128 + c0]);
  }
#pragma unroll
  for (int u = 0; u < 4; ++u) {
    float4 v = make_float4(acc[u * 4 + 0], acc[u * 4 + 1], acc[u * 4 + 2],
                           acc[u * 4 + 3]);
    ((float4*)(xout + (row0 + r) * 128 + c0))[u] = v;
  }
}

// ---------------------------------------------------------------------------

extern "C" void kernel_launch(void* const* d_in, const int* in_sizes, int n_in,
                              void* d_out, int out_size, void* d_ws,
                              size_t ws_size, hipStream_t stream) {
  const float* x   = (const float*)d_in[0];
  const float* pos = (const float*)d_in[1];
  // d_in[2] = batch (implied by layout, unused)
  const float* W1 = (const float*)d_in[3];
  const float* b1 = (const float*)d_in[4];
  const float* W2 = (const float*)d_in[5];
  const float* b2 = (const float*)d_in[6];
  const float* W3 = (const float*)d_in[7];
  const float* b3 = (const float*)d_in[8];
  const float* Wg = (const float*)d_in[9];
  const float* bg = (const float*)d_in[10];

  float* out = (float*)d_out;
  float* x_out = out;                                  // 8192*128
  float* pos_out = out + (size_t)NB * MP * 128;        // 8192*3
  float* batch_out = pos_out + (size_t)NB * MP * 3;    // 8192 (as float)

  char* ws = (char*)d_ws;
  int* fps_idx = (int*)ws;                             // 8192 ints
  int* nbr = (int*)(ws + 32768);                       // 8192*32 ints = 1 MB
  float* aggG = (float*)(ws + 32768 + (size_t)NB * MP * KN * 4);  // 4 MB

  hipLaunchKernelGGL(fps_kernel, dim3(NB), dim3(256), 0, stream, pos, fps_idx);
  hipLaunchKernelGGL(knn_kernel, dim3(NB * MP / 4), dim3(256), 0, stream, pos,
                     fps_idx, nbr, pos_out, batch_out);
  hipLaunchKernelGGL(mlp_kernel, dim3(NB * MP / 2), dim3(256), 0, stream, x,
                     pos, fps_idx, nbr, W1, b1, W2, b2, W3, b3, aggG);
  hipLaunchKernelGGL(wg_kernel, dim3(NB * MP / 32), dim3(256), 0, stream, aggG,
                     Wg, bg, x_out);
}

// Round 4
// 1564.017 us; speedup vs baseline: 2.7150x; 2.7150x over previous
//
#include <hip/hip_runtime.h>

typedef unsigned long long u64;
typedef unsigned int u32;

#define NB 4
#define NP 4096
#define MP 2048
#define KN 32
#define FD 64
#define CAP 512
#define PPT 16  // points per thread in fps (256 threads * 16 = 4096)

// Exact (non-contracted) squared distance, matching numpy's f32 evaluation
// order: ((dx*dx + dy*dy) + dz*dz), each op individually rounded.
__device__ __forceinline__ float dist2(float ax, float ay, float az,
                                       float bx, float by, float bz) {
  float dx = ax - bx, dy = ay - by, dz = az - bz;
  return __fadd_rn(__fadd_rn(__fmul_rn(dx, dx), __fmul_rn(dy, dy)),
                   __fmul_rn(dz, dz));
}

__device__ __forceinline__ void fma16(float* acc, float a, const float4* wp) {
#pragma unroll
  for (int u = 0; u < 4; ++u) {
    float4 wv = wp[u];
    acc[u * 4 + 0] = fmaf(a, wv.x, acc[u * 4 + 0]);
    acc[u * 4 + 1] = fmaf(a, wv.y, acc[u * 4 + 1]);
    acc[u * 4 + 2] = fmaf(a, wv.z, acc[u * 4 + 2]);
    acc[u * 4 + 3] = fmaf(a, wv.w, acc[u * 4 + 3]);
  }
}

// Wave64 max-reduce of a nonnegative f32 via DPP (identity 0 from bound_ctrl),
// result broadcast to all lanes through readlane(63).
__device__ __forceinline__ float wave_max_bcast(float x) {
  int v = __float_as_int(x);
#define DPP_STEP(ctrl)                                                     \
  {                                                                        \
    int o = __builtin_amdgcn_update_dpp(0, v, ctrl, 0xF, 0xF, true);       \
    v = __float_as_int(fmaxf(__int_as_float(v), __int_as_float(o)));       \
  }
  DPP_STEP(0x111)  // row_shr:1
  DPP_STEP(0x112)  // row_shr:2
  DPP_STEP(0x114)  // row_shr:4
  DPP_STEP(0x118)  // row_shr:8  -> lane 15/31/47/63 hold row maxes
  DPP_STEP(0x142)  // row_bcast15 -> lane31 = max(0..31), lane63 = max(32..63)
  DPP_STEP(0x143)  // row_bcast31 -> lane63 = max(0..63)
#undef DPP_STEP
  return __int_as_float(__builtin_amdgcn_readlane(v, 63));
}

// ---------------------------------------------------------------------------
// Kernel 1: farthest point sampling. One block per cloud, 256 threads,
// 16 points/thread in registers + a float4 LDS mirror. Per iteration:
//   - every lane SPECULATIVELY fetches its own candidate's coords from the
//     mirror (one ds_read_b128) in parallel with the DPP max + ballot
//   - the winner lane writes a (val,x,y,z) record + idx, ONE barrier
//   - all threads read 4 records (independent b128s) + idx int4, 3-compare
//     merge (strict > keeps lower wave = lower index on ties)
// Next center's coords come from the record — no dependent LDS read on the
// post-barrier path. __launch_bounds__(256,1) gives the full VGPR budget so
// no array gets demoted to LDS (round-3 failure mode).
// ---------------------------------------------------------------------------
__global__ __launch_bounds__(256, 1) void fps_kernel(
    const float* __restrict__ pos, int* __restrict__ fps_idx) {
  const int b = blockIdx.x;
  const float* p = pos + (size_t)b * NP * 3;
  __shared__ __align__(16) float4 sp[NP];      // 64 KB mirror (xyz + pad)
  __shared__ __align__(16) float4 recV[2][4];  // (val, x, y, z)
  __shared__ __align__(16) int recI[2][4];
  const int t = threadIdx.x;
  const int w = t >> 6;
  const int lane = t & 63;
  const int base = t * PPT;

  for (int i = t; i < NP; i += 256)
    sp[i] = make_float4(p[3 * i + 0], p[3 * i + 1], p[3 * i + 2], 0.0f);
  __syncthreads();

  float cx[PPT], cy[PPT], cz[PPT], mind[PPT];
  const float4 q0 = sp[0];
  float maxv = -1.0f;
  int maxj = 0;
#pragma unroll
  for (int j = 0; j < PPT; ++j) {
    const float4 v = sp[base + j];
    cx[j] = v.x; cy[j] = v.y; cz[j] = v.z;
    const float d = dist2(v.x, v.y, v.z, q0.x, q0.y, q0.z);
    mind[j] = d;
    if (d > maxv) { maxv = d; maxj = j; }  // strict >: first max
  }
  if (t == 0) fps_idx[b * MP] = 0;

  for (int it = 1; it < MP; ++it) {
    // ---- speculative fetch: my candidate's coords (overlaps the reduce) ----
    const float4 cand = sp[base + maxj];

    // ---- wave argmax; first max lane (lane order == index order) wins ----
    const float wmax = wave_max_bcast(maxv);
    const u64 bal = __ballot(maxv == wmax);
    const bool winner = (maxv == wmax) && ((bal & ((1ull << lane) - 1ull)) == 0);
    if (winner) {
      recV[it & 1][w] = make_float4(wmax, cand.x, cand.y, cand.z);
      recI[it & 1][w] = base + maxj;
    }
    __syncthreads();

    // ---- merge 4 wave records; strict > keeps lower wave on ties ----
    const float4 r0 = recV[it & 1][0], r1 = recV[it & 1][1];
    const float4 r2 = recV[it & 1][2], r3 = recV[it & 1][3];
    const int4 ri = *(const int4*)recI[it & 1];
    const bool s01 = r1.x > r0.x, s23 = r3.x > r2.x;
    const float4 ma = s01 ? r1 : r0;
    const int ia = s01 ? ri.y : ri.x;
    const float4 mb = s23 ? r3 : r2;
    const int ib = s23 ? ri.w : ri.z;
    const bool sab = mb.x > ma.x;
    const float4 mm = sab ? mb : ma;
    const int im = sab ? ib : ia;
    if (t == 0) fps_idx[b * MP + it] = im;

    // ---- update mind against new center (coords straight from record) ----
    const float ccx = mm.y, ccy = mm.z, ccz = mm.w;
    maxv = -1.0f; maxj = 0;
#pragma unroll
    for (int j = 0; j < PPT; ++j) {
      const float d = dist2(cx[j], cy[j], cz[j], ccx, ccy, ccz);
      const float nm = fminf(mind[j], d);
      mind[j] = nm;
      if (nm > maxv) { maxv = nm; maxj = j; }
    }
    // ping-pong slots + the single barrier make the next write safe: slot
    // (it&1) is rewritten only at it+2, after barrier(it+1) which follows
    // every wave's read of iteration it.
  }
}

// ---------------------------------------------------------------------------
// Kernel 2: radius-kNN. One wave per query (4 waves/block). Compacts all
// within-radius candidates into LDS (ballot compaction), then extracts the
// 32 smallest (d2,idx) keys via wave-wide u64 min-reduction.
// Also writes pos_out and batch_out (exact gathers).
// ---------------------------------------------------------------------------
__global__ __launch_bounds__(256) void knn_kernel(const float* __restrict__ pos,
                                                  const int* __restrict__ fps_idx,
                                                  int* __restrict__ nbr,
                                                  float* __restrict__ pos_out,
                                                  float* __restrict__ batch_out) {
  __shared__ u64 list[4][CAP];
  const int t = threadIdx.x;
  const int w = t >> 6;
  const int lane = t & 63;
  const int qg = blockIdx.x * 4 + w;  // 0..8191
  const int b = qg >> 11;
  const float* p = pos + (size_t)b * NP * 3;
  const int pidx = fps_idx[qg];
  const float qx = p[3 * pidx], qy = p[3 * pidx + 1], qz = p[3 * pidx + 2];

  int base = 0;
  for (int rnd = 0; rnd < NP / 64; ++rnd) {
    const int j = rnd * 64 + lane;
    const float d2 = dist2(p[3 * j], p[3 * j + 1], p[3 * j + 2], qx, qy, qz);
    const bool pred = (d2 <= 0.04f);  // 0.04f == f32(R*R) boundary, exact
    const u64 bal = __ballot(pred);
    if (pred) {
      const int slot = base + (int)__popcll(bal & ((1ull << lane) - 1ull));
      if (slot < CAP) list[w][slot] = ((u64)__float_as_uint(d2) << 32) | (u32)j;
    }
    base += (int)__popcll(bal);
  }
  const int L = base < CAP ? base : CAP;
  __syncthreads();

  u64 mk[8];
#pragma unroll
  for (int s = 0; s < 8; ++s) {
    const int sl = lane + s * 64;
    mk[s] = (sl < L) ? list[w][sl] : ~0ull;
  }
  u64 lmin = mk[0];
#pragma unroll
  for (int s = 1; s < 8; ++s) lmin = (mk[s] < lmin) ? mk[s] : lmin;

  int myNbr = -1;
  for (int r = 0; r < KN; ++r) {
    u64 m = lmin;
#pragma unroll
    for (int off = 32; off >= 1; off >>= 1) {
      u64 om = __shfl_xor(m, off, 64);
      m = (om < m) ? om : m;
    }
    if (m == ~0ull) break;  // wave-uniform: fewer than 32 in-radius
    if (lane == r) myNbr = (int)(m & 0xFFFFFFFFu);
    if (lmin == m) {  // exactly one lane (keys unique)
#pragma unroll
      for (int s = 0; s < 8; ++s) if (mk[s] == m) mk[s] = ~0ull;
      lmin = mk[0];
#pragma unroll
      for (int s = 1; s < 8; ++s) lmin = (mk[s] < lmin) ? mk[s] : lmin;
    }
  }
  if (lane < KN) nbr[(size_t)qg * KN + lane] = myNbr;
  if (lane == 0) {
    pos_out[qg * 3 + 0] = qx;
    pos_out[qg * 3 + 1] = qy;
    pos_out[qg * 3 + 2] = qz;
    batch_out[qg] = (float)b;
  }
}

// ---------------------------------------------------------------------------
// Kernel 3: gather + 3-layer MLP + masked max aggregation.
// Block = 256 threads handles 2 queries (64 neighbor rows). Weights staged
// per-layer into a shared 17KB buffer (W3 streamed in two k-halves).
// Aggregation: relu outputs >= 0 and self-neighbor always valid, so
// 0-initialized atomicMax on float bits is exact.
// ---------------------------------------------------------------------------
__global__ __launch_bounds__(256) void mlp_kernel(
    const float* __restrict__ x, const float* __restrict__ pos,
    const int* __restrict__ fps_idx, const int* __restrict__ nbr,
    const float* __restrict__ W1, const float* __restrict__ b1,
    const float* __restrict__ W2, const float* __restrict__ b2,
    const float* __restrict__ W3, const float* __restrict__ b3,
    float* __restrict__ aggG) {
  __shared__ __align__(16) float inB[64][68];  // 67 cols used (x .. rel)
  __shared__ __align__(16) float hB[64][68];
  __shared__ __align__(16) float wB[4352];     // W1(4288) / W2(4096) / W3-half(4096)
  __shared__ u32 agg[2][128];
  __shared__ int vrow[64];
  const int t = threadIdx.x;
  const int q0 = blockIdx.x * 2;

  ((u32*)agg)[t] = 0u;  // 256 entries exactly
  for (int i = t; i < 1072; i += 256) ((float4*)wB)[i] = ((const float4*)W1)[i];
  {
    const int r = t >> 2, qu = t & 3;
    const int qg = q0 + (r >> 5);
    const int nid = nbr[(size_t)qg * KN + (r & 31)];
    const int gid = (nid < 0) ? 0 : nid;
    const int bb = qg >> 11;
    const float4* xr =
        (const float4*)(x + ((size_t)bb * NP + gid) * FD + qu * 16);
#pragma unroll
    for (int u = 0; u < 4; ++u) {
      float4 v = xr[u];
      inB[r][qu * 16 + u * 4 + 0] = v.x;
      inB[r][qu * 16 + u * 4 + 1] = v.y;
      inB[r][qu * 16 + u * 4 + 2] = v.z;
      inB[r][qu * 16 + u * 4 + 3] = v.w;
    }
    if (qu == 0) {
      vrow[r] = nid;
      const float* p = pos + (size_t)bb * NP * 3;
      const int pidx = fps_idx[qg];
      inB[r][64] = p[3 * gid + 0] - p[3 * pidx + 0];
      inB[r][65] = p[3 * gid + 1] - p[3 * pidx + 1];
      inB[r][66] = p[3 * gid + 2] - p[3 * pidx + 2];
    }
  }
  __syncthreads();

  const int c0a = (t & 3) * 16;  // layers 1-2: 64 channels
  const int ra = t >> 2;         // row 0..63
  {  // ---- layer 1: 67 -> 64, relu ----
    float acc[16];
#pragma unroll
    for (int c = 0; c < 16; ++c) acc[c] = b1[c0a + c];
    for (int k = 0; k < 67; ++k)
      fma16(acc, inB[ra][k], (const float4*)&wB[k * 64 + c0a]);
#pragma unroll
    for (int c = 0; c < 16; ++c) hB[ra][c0a + c] = fmaxf(acc[c], 0.0f);
  }
  __syncthreads();
  for (int i = t; i < 1024; i += 256) ((float4*)wB)[i] = ((const float4*)W2)[i];
  __syncthreads();
  {  // ---- layer 2: 64 -> 64, relu (writes back into inB) ----
    float acc[16];
#pragma unroll
    for (int c = 0; c < 16; ++c) acc[c] = b2[c0a + c];
    for (int k = 0; k < 64; ++k)
      fma16(acc, hB[ra][k], (const float4*)&wB[k * 64 + c0a]);
#pragma unroll
    for (int c = 0; c < 16; ++c) inB[ra][c0a + c] = fmaxf(acc[c], 0.0f);
  }
  __syncthreads();

  // ---- layer 3: 64 -> 128 in two k-halves, then masked max aggregation ----
  const int c0b = (t & 7) * 16;
  const int r0 = (t >> 3) * 2;  // even row pair, never straddles a query
  float acc0[16], acc1[16];
#pragma unroll
  for (int c = 0; c < 16; ++c) { acc0[c] = b3[c0b + c]; acc1[c] = b3[c0b + c]; }
  for (int half = 0; half < 2; ++half) {
    for (int i = t; i < 1024; i += 256)
      ((float4*)wB)[i] = ((const float4*)(W3 + half * 32 * 128))[i];
    __syncthreads();
    for (int k = 0; k < 32; ++k) {
      const float a0 = inB[r0][half * 32 + k];
      const float a1 = inB[r0 + 1][half * 32 + k];
      const float4* wp = (const float4*)&wB[k * 128 + c0b];
      fma16(acc0, a0, wp);
      fma16(acc1, a1, wp);
    }
    __syncthreads();
  }
  {
    const int qq = r0 >> 5;
    const int v0 = vrow[r0], v1 = vrow[r0 + 1];
#pragma unroll
    for (int c = 0; c < 16; ++c) {
      float m = 0.0f;  // == max(0, .) folds the relu; exact (>=1 valid row/query)
      if (v0 >= 0) m = fmaxf(m, acc0[c]);
      if (v1 >= 0) m = fmaxf(m, acc1[c]);
      atomicMax(&agg[qq][c0b + c], __float_as_uint(m));
    }
  }
  __syncthreads();
  aggG[(size_t)(q0 + (t >> 7)) * 128 + (t & 127)] =
      __uint_as_float(agg[t >> 7][t & 127]);
}

// ---------------------------------------------------------------------------
// Kernel 4: out = agg @ Wg + bg. 32 rows/block; Wg staged in two k-halves.
// ---------------------------------------------------------------------------
__global__ __launch_bounds__(256) void wg_kernel(const float* __restrict__ aggG,
                                                 const float* __restrict__ Wg,
                                                 const float* __restrict__ bg,
                                                 float* __restrict__ xout) {
  __shared__ __align__(16) float wL[64 * 128];
  __shared__ __align__(16) float aL[32][132];
  const int t = threadIdx.x;
  const size_t row0 = (size_t)blockIdx.x * 32;
  for (int i = t; i < 1024; i += 256) {
    const int r = i >> 5, qd = i & 31;
    float4 v = ((const float4*)(aggG + (row0 + r) * 128))[qd];
    *((float4*)&aL[r][qd * 4]) = v;
  }
  const int r = t >> 3;
  const int c0 = (t & 7) * 16;
  float acc[16];
#pragma unroll
  for (int c = 0; c < 16; ++c) acc[c] = bg[c0 + c];
  for (int half = 0; half < 2; ++half) {
    __syncthreads();  // protects wL overwrite; also orders aL staging (half 0)
    for (int i = t; i < 2048; i += 256)
      ((float4*)wL)[i] = ((const float4*)(Wg + half * 64 * 128))[i];
    __syncthreads();
    for (int k = 0; k < 64; ++k)
      fma16(acc, aL[r][half * 64 + k], (const float4*)&wL[k * 128 + c0]);
  }
#pragma unroll
  for (int u = 0; u < 4; ++u) {
    float4 v = make_float4(acc[u * 4 + 0], acc[u * 4 + 1], acc[u * 4 + 2],
                           acc[u * 4 + 3]);
    ((float4*)(xout + (row0 + r) * 128 + c0))[u] = v;
  }
}

// ---------------------------------------------------------------------------

extern "C" void kernel_launch(void* const* d_in, const int* in_sizes, int n_in,
                              void* d_out, int out_size, void* d_ws,
                              size_t ws_size, hipStream_t stream) {
  const float* x   = (const float*)d_in[0];
  const float* pos = (const float*)d_in[1];
  // d_in[2] = batch (implied by layout, unused)
  const float* W1 = (const float*)d_in[3];
  const float* b1 = (const float*)d_in[4];
  const float* W2 = (const float*)d_in[5];
  const float* b2 = (const float*)d_in[6];
  const float* W3 = (const float*)d_in[7];
  const float* b3 = (const float*)d_in[8];
  const float* Wg = (const float*)d_in[9];
  const float* bg = (const float*)d_in[10];

  float* out = (float*)d_out;
  float* x_out = out;                                  // 8192*128
  float* pos_out = out + (size_t)NB * MP * 128;        // 8192*3
  float* batch_out = pos_out + (size_t)NB * MP * 3;    // 8192 (as float)

  char* ws = (char*)d_ws;
  int* fps_idx = (int*)ws;                             // 8192 ints
  int* nbr = (int*)(ws + 32768);                       // 8192*32 ints = 1 MB
  float* aggG = (float*)(ws + 32768 + (size_t)NB * MP * KN * 4);  // 4 MB

  hipLaunchKernelGGL(fps_kernel, dim3(NB), dim3(256), 0, stream, pos, fps_idx);
  hipLaunchKernelGGL(knn_kernel, dim3(NB * MP / 4), dim3(256), 0, stream, pos,
                     fps_idx, nbr, pos_out, batch_out);
  hipLaunchKernelGGL(mlp_kernel, dim3(NB * MP / 2), dim3(256), 0, stream, x,
                     pos, fps_idx, nbr, W1, b1, W2, b2, W3, b3, aggG);
  hipLaunchKernelGGL(wg_kernel, dim3(NB * MP / 32), dim3(256), 0, stream, aggG,
                     Wg, bg, x_out);
}

// Round 5
// 1307.366 us; speedup vs baseline: 3.2479x; 1.1963x over previous
//
#include <hip/hip_runtime.h>

typedef unsigned long long u64;
typedef unsigned int u32;
typedef float vf2 __attribute__((ext_vector_type(2)));

#define NB 4
#define NP 4096
#define MP 2048
#define KN 32
#define FD 64
#define CAP 512
#define PPT 16  // points per thread in fps (256 threads * 16 = 4096)

// Exact (non-contracted) squared distance, matching numpy's f32 evaluation
// order: ((dx*dx + dy*dy) + dz*dz), each op individually rounded.
__device__ __forceinline__ float dist2(float ax, float ay, float az,
                                       float bx, float by, float bz) {
  float dx = ax - bx, dy = ay - by, dz = az - bz;
  return __fadd_rn(__fadd_rn(__fmul_rn(dx, dx), __fmul_rn(dy, dy)),
                   __fmul_rn(dz, dz));
}

__device__ __forceinline__ void fma16(float* acc, float a, const float4* wp) {
#pragma unroll
  for (int u = 0; u < 4; ++u) {
    float4 wv = wp[u];
    acc[u * 4 + 0] = fmaf(a, wv.x, acc[u * 4 + 0]);
    acc[u * 4 + 1] = fmaf(a, wv.y, acc[u * 4 + 1]);
    acc[u * 4 + 2] = fmaf(a, wv.z, acc[u * 4 + 2]);
    acc[u * 4 + 3] = fmaf(a, wv.w, acc[u * 4 + 3]);
  }
}

// Wave64 max-reduce of a nonnegative f32 via DPP (identity 0 from bound_ctrl),
// result broadcast to all lanes through readlane(63).
__device__ __forceinline__ float wave_max_bcast(float x) {
  int v = __float_as_int(x);
#define DPP_STEP(ctrl)                                                     \
  {                                                                        \
    int o = __builtin_amdgcn_update_dpp(0, v, ctrl, 0xF, 0xF, true);       \
    v = __float_as_int(fmaxf(__int_as_float(v), __int_as_float(o)));       \
  }
  DPP_STEP(0x111)  // row_shr:1
  DPP_STEP(0x112)  // row_shr:2
  DPP_STEP(0x114)  // row_shr:4
  DPP_STEP(0x118)  // row_shr:8  -> lane 15/31/47/63 hold row maxes
  DPP_STEP(0x142)  // row_bcast15 -> lane31 = max(0..31), lane63 = max(32..63)
  DPP_STEP(0x143)  // row_bcast31 -> lane63 = max(0..63)
#undef DPP_STEP
  return __int_as_float(__builtin_amdgcn_readlane(v, 63));
}

// Exact packed squared distance for a point-pair against a scalar center.
// v_pk_sub/v_pk_mul/v_pk_add round each 32-bit half exactly like the scalar
// ops; the empty asm on each product blocks FMA contraction (belt) on top of
// the fp-contract(off) pragma in the caller (braces).
__device__ __forceinline__ vf2 dist2_pk(vf2 cx, vf2 cy, vf2 cz, float bx,
                                        float by, float bz) {
  vf2 dx = cx - bx, dy = cy - by, dz = cz - bz;
  vf2 xx = dx * dx;
  vf2 yy = dy * dy;
  vf2 zz = dz * dz;
  asm("" : "+v"(xx));
  asm("" : "+v"(yy));
  asm("" : "+v"(zz));
  vf2 s = xx + yy;
  asm("" : "+v"(s));
  return s + zz;
}

// ---------------------------------------------------------------------------
// Kernel 1: farthest point sampling. One block per cloud, 256 threads,
// 16 points/thread held as 8 vf2 PAIRS in registers (packed dual-FP32 update:
// v_pk_sub/mul/add halve the issue count of the 16-point distance update).
// Per iteration: DPP wave max + ballot (first lane = lowest index wins ties),
// winner writes a u64 key to a ping-pong LDS slot, ONE barrier, all threads
// merge 4 keys (u64 > keeps max val, ties -> smaller index via 4095-idx
// packing) and read the center's coords from the LDS mirror.
// __launch_bounds__(256,1): full VGPR budget, no LDS demotion (round-3 bug).
// ---------------------------------------------------------------------------
__global__ __launch_bounds__(256, 1) void fps_kernel(
    const float* __restrict__ pos, int* __restrict__ fps_idx) {
#pragma clang fp contract(off)
  const int b = blockIdx.x;
  const float* p = pos + (size_t)b * NP * 3;
  __shared__ __align__(16) float2 sxy[NP];  // 32 KB
  __shared__ float sz[NP];                  // 16 KB
  __shared__ u64 keys[2][4];
  const int t = threadIdx.x;
  const int w = t >> 6;
  const int lane = t & 63;
  const int base = t * PPT;

  for (int i = t; i < NP; i += 256) {
    sxy[i] = make_float2(p[3 * i + 0], p[3 * i + 1]);
    sz[i] = p[3 * i + 2];
  }
  __syncthreads();

  vf2 cx[8], cy[8], cz[8], mind[8];
  const float2 q0 = sxy[0];
  const float q0z = sz[0];
  float maxv = -1.0f;
  int maxi = base;
#pragma unroll
  for (int u = 0; u < 8; ++u) {
    const float2 a = sxy[base + 2 * u];
    const float2 bb = sxy[base + 2 * u + 1];
    cx[u] = (vf2){a.x, bb.x};
    cy[u] = (vf2){a.y, bb.y};
    cz[u] = (vf2){sz[base + 2 * u], sz[base + 2 * u + 1]};
    const vf2 d2 = dist2_pk(cx[u], cy[u], cz[u], q0.x, q0.y, q0z);
    mind[u] = d2;
    if (d2.x > maxv) { maxv = d2.x; maxi = base + 2 * u; }      // strict >:
    if (d2.y > maxv) { maxv = d2.y; maxi = base + 2 * u + 1; }  // first max
  }
  if (t == 0) fps_idx[b * MP] = 0;

  for (int it = 1; it < MP; ++it) {
    // ---- wave argmax; first max lane (lane order == index order) wins ----
    const float wmax = wave_max_bcast(maxv);
    const u64 bal = __ballot(maxv == wmax);
    const bool winner = (maxv == wmax) && ((bal & ((1ull << lane) - 1ull)) == 0);
    if (winner)
      keys[it & 1][w] = ((u64)__float_as_uint(wmax) << 32) | (u32)(NP - 1 - maxi);
    __syncthreads();

    // ---- merge 4 wave keys; u64 > = max val, ties -> smaller index ----
    const u64 k0 = keys[it & 1][0], k1 = keys[it & 1][1];
    const u64 k2 = keys[it & 1][2], k3 = keys[it & 1][3];
    const u64 ka = (k1 > k0) ? k1 : k0;
    const u64 kb = (k3 > k2) ? k3 : k2;
    const u64 km = (kb > ka) ? kb : ka;
    const int gidx = NP - 1 - (int)(km & 0xFFFFFFFFu);
    if (t == 0) fps_idx[b * MP + it] = gidx;
    const float2 cc = sxy[gidx];
    const float ccz = sz[gidx];

    // ---- packed update of 8 point-pairs against the new center ----
    maxv = -1.0f;
    maxi = base;
#pragma unroll
    for (int u = 0; u < 8; ++u) {
      const vf2 d2 = dist2_pk(cx[u], cy[u], cz[u], cc.x, cc.y, ccz);
      const float m0 = fminf(mind[u].x, d2.x);
      const float m1 = fminf(mind[u].y, d2.y);
      mind[u].x = m0;
      mind[u].y = m1;
      if (m0 > maxv) { maxv = m0; maxi = base + 2 * u; }
      if (m1 > maxv) { maxv = m1; maxi = base + 2 * u + 1; }
    }
    // ping-pong slots + the single barrier make the next write safe: slot
    // (it&1) is rewritten only at it+2, after barrier(it+1) which follows
    // every wave's read of iteration it.
  }
}

// ---------------------------------------------------------------------------
// Kernel 2: radius-kNN. One wave per query (4 waves/block). Compacts all
// within-radius candidates into LDS (ballot compaction), then extracts the
// 32 smallest (d2,idx) keys via wave-wide u64 min-reduction.
// Also writes pos_out and batch_out (exact gathers).
// ---------------------------------------------------------------------------
__global__ __launch_bounds__(256) void knn_kernel(const float* __restrict__ pos,
                                                  const int* __restrict__ fps_idx,
                                                  int* __restrict__ nbr,
                                                  float* __restrict__ pos_out,
                                                  float* __restrict__ batch_out) {
  __shared__ u64 list[4][CAP];
  const int t = threadIdx.x;
  const int w = t >> 6;
  const int lane = t & 63;
  const int qg = blockIdx.x * 4 + w;  // 0..8191
  const int b = qg >> 11;
  const float* p = pos + (size_t)b * NP * 3;
  const int pidx = fps_idx[qg];
  const float qx = p[3 * pidx], qy = p[3 * pidx + 1], qz = p[3 * pidx + 2];

  int base = 0;
  for (int rnd = 0; rnd < NP / 64; ++rnd) {
    const int j = rnd * 64 + lane;
    const float d2 = dist2(p[3 * j], p[3 * j + 1], p[3 * j + 2], qx, qy, qz);
    const bool pred = (d2 <= 0.04f);  // 0.04f == f32(R*R) boundary, exact
    const u64 bal = __ballot(pred);
    if (pred) {
      const int slot = base + (int)__popcll(bal & ((1ull << lane) - 1ull));
      if (slot < CAP) list[w][slot] = ((u64)__float_as_uint(d2) << 32) | (u32)j;
    }
    base += (int)__popcll(bal);
  }
  const int L = base < CAP ? base : CAP;
  __syncthreads();

  u64 mk[8];
#pragma unroll
  for (int s = 0; s < 8; ++s) {
    const int sl = lane + s * 64;
    mk[s] = (sl < L) ? list[w][sl] : ~0ull;
  }
  u64 lmin = mk[0];
#pragma unroll
  for (int s = 1; s < 8; ++s) lmin = (mk[s] < lmin) ? mk[s] : lmin;

  int myNbr = -1;
  for (int r = 0; r < KN; ++r) {
    u64 m = lmin;
#pragma unroll
    for (int off = 32; off >= 1; off >>= 1) {
      u64 om = __shfl_xor(m, off, 64);
      m = (om < m) ? om : m;
    }
    if (m == ~0ull) break;  // wave-uniform: fewer than 32 in-radius
    if (lane == r) myNbr = (int)(m & 0xFFFFFFFFu);
    if (lmin == m) {  // exactly one lane (keys unique)
#pragma unroll
      for (int s = 0; s < 8; ++s) if (mk[s] == m) mk[s] = ~0ull;
      lmin = mk[0];
#pragma unroll
      for (int s = 1; s < 8; ++s) lmin = (mk[s] < lmin) ? mk[s] : lmin;
    }
  }
  if (lane < KN) nbr[(size_t)qg * KN + lane] = myNbr;
  if (lane == 0) {
    pos_out[qg * 3 + 0] = qx;
    pos_out[qg * 3 + 1] = qy;
    pos_out[qg * 3 + 2] = qz;
    batch_out[qg] = (float)b;
  }
}

// ---------------------------------------------------------------------------
// Kernel 3: gather + 3-layer MLP + masked max aggregation.
// Block = 256 threads handles 2 queries (64 neighbor rows). Weights staged
// per-layer into a shared 17KB buffer (W3 streamed in two k-halves).
// Aggregation: relu outputs >= 0 and self-neighbor always valid, so
// 0-initialized atomicMax on float bits is exact.
// ---------------------------------------------------------------------------
__global__ __launch_bounds__(256) void mlp_kernel(
    const float* __restrict__ x, const float* __restrict__ pos,
    const int* __restrict__ fps_idx, const int* __restrict__ nbr,
    const float* __restrict__ W1, const float* __restrict__ b1,
    const float* __restrict__ W2, const float* __restrict__ b2,
    const float* __restrict__ W3, const float* __restrict__ b3,
    float* __restrict__ aggG) {
  __shared__ __align__(16) float inB[64][68];  // 67 cols used (x .. rel)
  __shared__ __align__(16) float hB[64][68];
  __shared__ __align__(16) float wB[4352];     // W1(4288) / W2(4096) / W3-half(4096)
  __shared__ u32 agg[2][128];
  __shared__ int vrow[64];
  const int t = threadIdx.x;
  const int q0 = blockIdx.x * 2;

  ((u32*)agg)[t] = 0u;  // 256 entries exactly
  for (int i = t; i < 1072; i += 256) ((float4*)wB)[i] = ((const float4*)W1)[i];
  {
    const int r = t >> 2, qu = t & 3;
    const int qg = q0 + (r >> 5);
    const int nid = nbr[(size_t)qg * KN + (r & 31)];
    const int gid = (nid < 0) ? 0 : nid;
    const int bb = qg >> 11;
    const float4* xr =
        (const float4*)(x + ((size_t)bb * NP + gid) * FD + qu * 16);
#pragma unroll
    for (int u = 0; u < 4; ++u) {
      float4 v = xr[u];
      inB[r][qu * 16 + u * 4 + 0] = v.x;
      inB[r][qu * 16 + u * 4 + 1] = v.y;
      inB[r][qu * 16 + u * 4 + 2] = v.z;
      inB[r][qu * 16 + u * 4 + 3] = v.w;
    }
    if (qu == 0) {
      vrow[r] = nid;
      const float* p = pos + (size_t)bb * NP * 3;
      const int pidx = fps_idx[qg];
      inB[r][64] = p[3 * gid + 0] - p[3 * pidx + 0];
      inB[r][65] = p[3 * gid + 1] - p[3 * pidx + 1];
      inB[r][66] = p[3 * gid + 2] - p[3 * pidx + 2];
    }
  }
  __syncthreads();

  const int c0a = (t & 3) * 16;  // layers 1-2: 64 channels
  const int ra = t >> 2;         // row 0..63
  {  // ---- layer 1: 67 -> 64, relu ----
    float acc[16];
#pragma unroll
    for (int c = 0; c < 16; ++c) acc[c] = b1[c0a + c];
    for (int k = 0; k < 67; ++k)
      fma16(acc, inB[ra][k], (const float4*)&wB[k * 64 + c0a]);
#pragma unroll
    for (int c = 0; c < 16; ++c) hB[ra][c0a + c] = fmaxf(acc[c], 0.0f);
  }
  __syncthreads();
  for (int i = t; i < 1024; i += 256) ((float4*)wB)[i] = ((const float4*)W2)[i];
  __syncthreads();
  {  // ---- layer 2: 64 -> 64, relu (writes back into inB) ----
    float acc[16];
#pragma unroll
    for (int c = 0; c < 16; ++c) acc[c] = b2[c0a + c];
    for (int k = 0; k < 64; ++k)
      fma16(acc, hB[ra][k], (const float4*)&wB[k * 64 + c0a]);
#pragma unroll
    for (int c = 0; c < 16; ++c) inB[ra][c0a + c] = fmaxf(acc[c], 0.0f);
  }
  __syncthreads();

  // ---- layer 3: 64 -> 128 in two k-halves, then masked max aggregation ----
  const int c0b = (t & 7) * 16;
  const int r0 = (t >> 3) * 2;  // even row pair, never straddles a query
  float acc0[16], acc1[16];
#pragma unroll
  for (int c = 0; c < 16; ++c) { acc0[c] = b3[c0b + c]; acc1[c] = b3[c0b + c]; }
  for (int half = 0; half < 2; ++half) {
    for (int i = t; i < 1024; i += 256)
      ((float4*)wB)[i] = ((const float4*)(W3 + half * 32 * 128))[i];
    __syncthreads();
    for (int k = 0; k < 32; ++k) {
      const float a0 = inB[r0][half * 32 + k];
      const float a1 = inB[r0 + 1][half * 32 + k];
      const float4* wp = (const float4*)&wB[k * 128 + c0b];
      fma16(acc0, a0, wp);
      fma16(acc1, a1, wp);
    }
    __syncthreads();
  }
  {
    const int qq = r0 >> 5;
    const int v0 = vrow[r0], v1 = vrow[r0 + 1];
#pragma unroll
    for (int c = 0; c < 16; ++c) {
      float m = 0.0f;  // == max(0, .) folds the relu; exact (>=1 valid row/query)
      if (v0 >= 0) m = fmaxf(m, acc0[c]);
      if (v1 >= 0) m = fmaxf(m, acc1[c]);
      atomicMax(&agg[qq][c0b + c], __float_as_uint(m));
    }
  }
  __syncthreads();
  aggG[(size_t)(q0 + (t >> 7)) * 128 + (t & 127)] =
      __uint_as_float(agg[t >> 7][t & 127]);
}

// ---------------------------------------------------------------------------
// Kernel 4: out = agg @ Wg + bg. 32 rows/block; Wg staged in two k-halves.
// ---------------------------------------------------------------------------
__global__ __launch_bounds__(256) void wg_kernel(const float* __restrict__ aggG,
                                                 const float* __restrict__ Wg,
                                                 const float* __restrict__ bg,
                                                 float* __restrict__ xout) {
  __shared__ __align__(16) float wL[64 * 128];
  __shared__ __align__(16) float aL[32][132];
  const int t = threadIdx.x;
  const size_t row0 = (size_t)blockIdx.x * 32;
  for (int i = t; i < 1024; i += 256) {
    const int r = i >> 5, qd = i & 31;
    float4 v = ((const float4*)(aggG + (row0 + r) * 128))[qd];
    *((float4*)&aL[r][qd * 4]) = v;
  }
  const int r = t >> 3;
  const int c0 = (t & 7) * 16;
  float acc[16];
#pragma unroll
  for (int c = 0; c < 16; ++c) acc[c] = bg[c0 + c];
  for (int half = 0; half < 2; ++half) {
    __syncthreads();  // protects wL overwrite; also orders aL staging (half 0)
    for (int i = t; i < 2048; i += 256)
      ((float4*)wL)[i] = ((const float4*)(Wg + half * 64 * 128))[i];
    __syncthreads();
    for (int k = 0; k < 64; ++k)
      fma16(acc, aL[r][half * 64 + k], (const float4*)&wL[k * 128 + c0]);
  }
#pragma unroll
  for (int u = 0; u < 4; ++u) {
    float4 v = make_float4(acc[u * 4 + 0], acc[u * 4 + 1], acc[u * 4 + 2],
                           acc[u * 4 + 3]);
    ((float4*)(xout + (row0 + r) * 128 + c0))[u] = v;
  }
}

// ---------------------------------------------------------------------------

extern "C" void kernel_launch(void* const* d_in, const int* in_sizes, int n_in,
                              void* d_out, int out_size, void* d_ws,
                              size_t ws_size, hipStream_t stream) {
  const float* x   = (const float*)d_in[0];
  const float* pos = (const float*)d_in[1];
  // d_in[2] = batch (implied by layout, unused)
  const float* W1 = (const float*)d_in[3];
  const float* b1 = (const float*)d_in[4];
  const float* W2 = (const float*)d_in[5];
  const float* b2 = (const float*)d_in[6];
  const float* W3 = (const float*)d_in[7];
  const float* b3 = (const float*)d_in[8];
  const float* Wg = (const float*)d_in[9];
  const float* bg = (const float*)d_in[10];

  float* out = (float*)d_out;
  float* x_out = out;                                  // 8192*128
  float* pos_out = out + (size_t)NB * MP * 128;        // 8192*3
  float* batch_out = pos_out + (size_t)NB * MP * 3;    // 8192 (as float)

  char* ws = (char*)d_ws;
  int* fps_idx = (int*)ws;                             // 8192 ints
  int* nbr = (int*)(ws + 32768);                       // 8192*32 ints = 1 MB
  float* aggG = (float*)(ws + 32768 + (size_t)NB * MP * KN * 4);  // 4 MB

  hipLaunchKernelGGL(fps_kernel, dim3(NB), dim3(256), 0, stream, pos, fps_idx);
  hipLaunchKernelGGL(knn_kernel, dim3(NB * MP / 4), dim3(256), 0, stream, pos,
                     fps_idx, nbr, pos_out, batch_out);
  hipLaunchKernelGGL(mlp_kernel, dim3(NB * MP / 2), dim3(256), 0, stream, x,
                     pos, fps_idx, nbr, W1, b1, W2, b2, W3, b3, aggG);
  hipLaunchKernelGGL(wg_kernel, dim3(NB * MP / 32), dim3(256), 0, stream, aggG,
                     Wg, bg, x_out);
}